// Round 2
// baseline (211.205 us; speedup 1.0000x reference)
//
#include <hip/hip_runtime.h>
#include <hip/hip_bf16.h>

typedef __attribute__((ext_vector_type(8))) short short8;
typedef __attribute__((ext_vector_type(4))) float floatx4;

#define MFMA16(a, b, c) __builtin_amdgcn_mfma_f32_16x16x32_bf16((a), (b), (c), 0, 0, 0)
#define WAIT_VM(N) asm volatile("s_waitcnt vmcnt(" #N ")" ::: "memory")
#define BAR() __builtin_amdgcn_s_barrier()

__device__ __forceinline__ short f2bf(float f) {
    union { float f; unsigned u; } x; x.f = f;
    unsigned r = (x.u + 0x7fffu + ((x.u >> 16) & 1u)) >> 16;
    return (short)r;
}

// async global->LDS, 16B per lane; LDS dest is wave-uniform base + lane*16
__device__ __forceinline__ void gl2lds16(const short* g, short* l) {
    void* gv = const_cast<short*>(g);
    __builtin_amdgcn_global_load_lds((__attribute__((address_space(1))) void*)gv,
                                     (__attribute__((address_space(3))) void*)l,
                                     16, 0, 0);
}

// ------------- weight prep: 4 transposes (fp32->bf16) + bias concat, one launch -------------
__global__ void transpose_w4(const float* __restrict__ Wq, const float* __restrict__ Wk,
                             const float* __restrict__ Wv, const float* __restrict__ Wn,
                             const float* __restrict__ bq, const float* __restrict__ bk,
                             const float* __restrict__ bv,
                             short* __restrict__ Wqkv_t, short* __restrict__ Wn_t,
                             float* __restrict__ bias_cat) {
    __shared__ float t[32][33];
    int z = blockIdx.z;
    const float* Wsrc = (z == 0) ? Wq : (z == 1) ? Wk : (z == 2) ? Wv : Wn;
    int o0 = blockIdx.x * 32, c0 = blockIdx.y * 32;
    int lx = threadIdx.x, ly = threadIdx.y;   // (32,8)
    for (int i = ly; i < 32; i += 8) t[i][lx] = Wsrc[(size_t)(c0 + i) * 512 + o0 + lx];
    __syncthreads();
    for (int i = ly; i < 32; i += 8) {
        short v = f2bf(t[lx][i]);
        if (z < 3) Wqkv_t[(size_t)(z * 512 + o0 + i) * 512 + c0 + lx] = v;
        else       Wn_t[(size_t)(o0 + i) * 512 + c0 + lx] = v;
    }
    if (z < 3 && blockIdx.y == 0 && ly == 0) {
        const float* bsrc = (z == 0) ? bq : (z == 1) ? bk : bv;
        bias_cat[z * 512 + o0 + lx] = bsrc[o0 + lx];
    }
}

// ---------------- groupnorm: x[b][c][p] -> hnt[b][p][c] bf16 ----------------
__global__ __launch_bounds__(256) void groupnorm_k(const float* __restrict__ x,
                                                   short* __restrict__ hnt) {
    int b = blockIdx.x >> 5, g = blockIdx.x & 31;
    const float* xg = x + ((size_t)b * 512 + g * 16) * 1024;   // 16 rows x 1024
    const float4* xg4 = (const float4*)xg;
    float s = 0.f, ss = 0.f;
    for (int i = threadIdx.x; i < 4096; i += 256) {
        float4 v = xg4[i];
        s  += v.x + v.y + v.z + v.w;
        ss += v.x * v.x + v.y * v.y + v.z * v.z + v.w * v.w;
    }
#pragma unroll
    for (int off = 32; off > 0; off >>= 1) {
        s  += __shfl_down(s,  off, 64);
        ss += __shfl_down(ss, off, 64);
    }
    __shared__ float red[8];
    int w = threadIdx.x >> 6;
    if ((threadIdx.x & 63) == 0) { red[w] = s; red[4 + w] = ss; }
    __syncthreads();
    float S  = red[0] + red[1] + red[2] + red[3];
    float SS = red[4] + red[5] + red[6] + red[7];
    float mean = S * (1.f / 16384.f);
    float var  = SS * (1.f / 16384.f) - mean * mean;
    float rstd = rsqrtf(var + 1e-5f);
    __shared__ __attribute__((aligned(16))) short tile[16 * 1026];
    for (int i = threadIdx.x; i < 4096; i += 256) {
        float4 v = xg4[i];
        int c = i >> 8, p = (i & 255) * 4;
        short* tp = tile + c * 1026 + p;
        tp[0] = f2bf((v.x - mean) * rstd);
        tp[1] = f2bf((v.y - mean) * rstd);
        tp[2] = f2bf((v.z - mean) * rstd);
        tp[3] = f2bf((v.w - mean) * rstd);
    }
    __syncthreads();
    for (int i = threadIdx.x; i < 2048; i += 256) {
        int p = i >> 1, half = i & 1;
        short8 v;
#pragma unroll
        for (int j = 0; j < 8; ++j) v[j] = tile[(half * 8 + j) * 1026 + p];
        *(short8*)(hnt + ((size_t)b * 1024 + p) * 512 + g * 16 + half * 8) = v;
    }
}

// ---------------- fused QKV GEMM: N=1536 over concat weights ----------------
// 3-stage LDS pipeline, prefetch distance 2, counted vmcnt (never drain in main loop),
// raw s_barrier so loads stay in flight across barriers.
__global__ __launch_bounds__(256) void qkv_gemm(const short* __restrict__ A,
                                                const short* __restrict__ Wt,
                                                const float* __restrict__ bias_cat,
                                                short* __restrict__ Qp,
                                                short* __restrict__ Kp,
                                                short* __restrict__ Vb) {
    const int tid = threadIdx.x;
    const int wv = tid >> 6, ln = tid & 63;
    const int m0 = blockIdx.x * 128, n0 = blockIdx.y * 128;
    const size_t BS = 1024 * 512;
    const short* Ab = A + (size_t)blockIdx.z * BS;
    const int tsel = n0 >> 9;
    const int permute = (tsel < 2);
    short* Ob = ((tsel == 0) ? Qp : (tsel == 1) ? Kp : Vb) + (size_t)blockIdx.z * BS;

    __shared__ __attribute__((aligned(16))) short As[3][128 * 32];
    __shared__ __attribute__((aligned(16))) short Bs[3][128 * 32];

    floatx4 acc[4][4] = {};
    const int wm = (wv >> 1) * 64, wn = (wv & 1) * 64;
    const int fr = ln & 15, fq = ln >> 4;

    int sr[2], sq[2];
#pragma unroll
    for (int j = 0; j < 2; ++j) {
        int s = (wv * 2 + j) * 64 + ln;
        sr[j] = s >> 2;
        sq[j] = ((s & 3) ^ ((sr[j] >> 1) & 3)) * 8;
    }

    short* a0 = &As[0][0]; short* a1 = &As[1][0]; short* a2 = &As[2][0];
    short* b0 = &Bs[0][0]; short* b1 = &Bs[1][0]; short* b2 = &Bs[2][0];

    // stage tiles 0 and 1 (4 loads each per wave)
#pragma unroll
    for (int j = 0; j < 2; ++j) {
        gl2lds16(Ab + (size_t)(m0 + sr[j]) * 512 + sq[j],      a0 + (wv * 2 + j) * 512);
        gl2lds16(Wt + (size_t)(n0 + sr[j]) * 512 + sq[j],      b0 + (wv * 2 + j) * 512);
        gl2lds16(Ab + (size_t)(m0 + sr[j]) * 512 + 32 + sq[j], a1 + (wv * 2 + j) * 512);
        gl2lds16(Wt + (size_t)(n0 + sr[j]) * 512 + 32 + sq[j], b1 + (wv * 2 + j) * 512);
    }

    auto compute = [&](const short* Ap, const short* Bp) {
        short8 af[4], bfr[4];
#pragma unroll
        for (int t = 0; t < 4; ++t) {
            int ra = wm + t * 16 + fr;
            af[t]  = *(const short8*)(Ap + ra * 32 + ((fq ^ ((ra >> 1) & 3)) * 8));
            int rb = wn + t * 16 + fr;
            bfr[t] = *(const short8*)(Bp + rb * 32 + ((fq ^ ((rb >> 1) & 3)) * 8));
        }
#pragma unroll
        for (int mt = 0; mt < 4; ++mt)
#pragma unroll
            for (int nt = 0; nt < 4; ++nt)
                acc[mt][nt] = MFMA16(af[mt], bfr[nt], acc[mt][nt]);
    };

    for (int t = 0; t < 14; ++t) {
        int kp = t * 32 + 64;   // prefetch tile t+2
#pragma unroll
        for (int j = 0; j < 2; ++j) {
            gl2lds16(Ab + (size_t)(m0 + sr[j]) * 512 + kp + sq[j], a2 + (wv * 2 + j) * 512);
            gl2lds16(Wt + (size_t)(n0 + sr[j]) * 512 + kp + sq[j], b2 + (wv * 2 + j) * 512);
        }
        WAIT_VM(8);            // tile t's 4 loads (oldest) done; t+1,t+2 still in flight
        BAR();
        compute(a0, b0);
        BAR();                 // all waves done reading tile t's buffer; safe to DMA into it
        short* ta = a0; a0 = a1; a1 = a2; a2 = ta;
        short* tb = b0; b0 = b1; b1 = b2; b2 = tb;
    }
    WAIT_VM(4); BAR();
    compute(a0, b0);           // tile 14
    WAIT_VM(0); BAR();
    compute(a1, b1);           // tile 15

#pragma unroll
    for (int mt = 0; mt < 4; ++mt) {
#pragma unroll
        for (int nt = 0; nt < 4; ++nt) {
            int n = n0 + wn + nt * 16 + fr;
            float bvv = bias_cat[n];
            int nn = n & 511;
#pragma unroll
            for (int r = 0; r < 4; ++r) {
                int m = m0 + wm + mt * 16 + fq * 4 + r;
                int mrow = permute ? ((m & 31) * 32 + (m >> 5)) : m;
                Ob[(size_t)mrow * 512 + nn] = f2bf(acc[mt][nt][r] + bvv);
            }
        }
    }
}

// ---------------- fused S-GEMM + per-32x32-block softmax diagonal, 128x256 tiles ----------------
__global__ __launch_bounds__(256, 2) void attn_sm(const short* __restrict__ Qp,
                                                  const short* __restrict__ Kp,
                                                  float* __restrict__ Dm) {
    const int tid = threadIdx.x;
    const int wv = tid >> 6, ln = tid & 63;
    const int m0 = blockIdx.x * 128, n0 = blockIdx.y * 256, b = blockIdx.z;
    const short* Qb = Qp + (size_t)b * (1024 * 512);
    const short* Kb = Kp + (size_t)b * (1024 * 512);

    __shared__ __attribute__((aligned(16))) short As[3][128 * 32];
    __shared__ __attribute__((aligned(16))) short Bs[3][256 * 32];

    floatx4 acc[4][8] = {};
    const int wm = (wv >> 1) * 64, wn = (wv & 1) * 128;
    const int fr = ln & 15, fq = ln >> 4;

    int ar[2], aq[2], br[4], bq_[4];
#pragma unroll
    for (int j = 0; j < 2; ++j) {
        int s = (wv * 2 + j) * 64 + ln;
        ar[j] = s >> 2;
        aq[j] = ((s & 3) ^ ((ar[j] >> 1) & 3)) * 8;
    }
#pragma unroll
    for (int j = 0; j < 4; ++j) {
        int s = (wv * 4 + j) * 64 + ln;
        br[j] = s >> 2;
        bq_[j] = ((s & 3) ^ ((br[j] >> 1) & 3)) * 8;
    }

    short* a0 = &As[0][0]; short* a1 = &As[1][0]; short* a2 = &As[2][0];
    short* b0 = &Bs[0][0]; short* b1 = &Bs[1][0]; short* b2 = &Bs[2][0];

    // stage tiles 0 and 1 (6 loads each per wave)
#pragma unroll
    for (int j = 0; j < 2; ++j) {
        gl2lds16(Qb + (size_t)(m0 + ar[j]) * 512 + aq[j],      a0 + (wv * 2 + j) * 512);
        gl2lds16(Qb + (size_t)(m0 + ar[j]) * 512 + 32 + aq[j], a1 + (wv * 2 + j) * 512);
    }
#pragma unroll
    for (int j = 0; j < 4; ++j) {
        gl2lds16(Kb + (size_t)(n0 + br[j]) * 512 + bq_[j],      b0 + (wv * 4 + j) * 512);
        gl2lds16(Kb + (size_t)(n0 + br[j]) * 512 + 32 + bq_[j], b1 + (wv * 4 + j) * 512);
    }

    auto compute = [&](const short* Ap, const short* Bp) {
        short8 af[4], bfr[8];
#pragma unroll
        for (int t = 0; t < 4; ++t) {
            int ra = wm + t * 16 + fr;
            af[t] = *(const short8*)(Ap + ra * 32 + ((fq ^ ((ra >> 1) & 3)) * 8));
        }
#pragma unroll
        for (int u = 0; u < 8; ++u) {
            int rb = wn + u * 16 + fr;
            bfr[u] = *(const short8*)(Bp + rb * 32 + ((fq ^ ((rb >> 1) & 3)) * 8));
        }
#pragma unroll
        for (int mt = 0; mt < 4; ++mt)
#pragma unroll
            for (int nt = 0; nt < 8; ++nt)
                acc[mt][nt] = MFMA16(af[mt], bfr[nt], acc[mt][nt]);
    };

    for (int t = 0; t < 14; ++t) {
        int kp = t * 32 + 64;   // prefetch tile t+2
#pragma unroll
        for (int j = 0; j < 2; ++j)
            gl2lds16(Qb + (size_t)(m0 + ar[j]) * 512 + kp + aq[j], a2 + (wv * 2 + j) * 512);
#pragma unroll
        for (int j = 0; j < 4; ++j)
            gl2lds16(Kb + (size_t)(n0 + br[j]) * 512 + kp + bq_[j], b2 + (wv * 4 + j) * 512);
        WAIT_VM(12);           // tile t's 6 loads done; 12 newer in flight
        BAR();
        compute(a0, b0);
        BAR();
        short* ta = a0; a0 = a1; a1 = a2; a2 = ta;
        short* tb = b0; b0 = b1; b1 = b2; b2 = tb;
    }
    WAIT_VM(6); BAR();
    compute(a0, b0);           // tile 14
    WAIT_VM(0); BAR();
    compute(a1, b1);           // tile 15

    // ---- per-slice softmax-diagonal (2x4 = 8 slices per wave) ----
    const float scale = 0.04419417382415922f;  // 512^-0.5
    const int wbase = (m0 + wm) >> 5;
    const int Wbase = (n0 + wn) >> 5;
#pragma unroll
    for (int si = 0; si < 2; ++si) {
#pragma unroll
        for (int sj = 0; sj < 4; ++sj) {
            int wg = wbase + si, Wg = Wbase + sj;
            float tv[16];
            float mx = -3.0e38f;
#pragma unroll
            for (int mi = 0; mi < 2; ++mi)
#pragma unroll
                for (int ni = 0; ni < 2; ++ni)
#pragma unroll
                    for (int r = 0; r < 4; ++r) {
                        float u = acc[2 * si + mi][2 * sj + ni][r] * scale;
                        tv[(mi * 2 + ni) * 4 + r] = u;
                        mx = fmaxf(mx, u);
                    }
#pragma unroll
            for (int off = 32; off > 0; off >>= 1) mx = fmaxf(mx, __shfl_xor(mx, off, 64));
            float se = 0.f;
#pragma unroll
            for (int i = 0; i < 16; ++i) se += __expf(tv[i] - mx);
#pragma unroll
            for (int off = 32; off > 0; off >>= 1) se += __shfl_xor(se, off, 64);
            if (fq == ((wg >> 2) & 3) && fr == (Wg & 15)) {
                int mi = wg >> 4, ni = Wg >> 4;
                float numer = tv[(mi * 2 + ni) * 4 + (wg & 3)];
                Dm[((size_t)b * 32 + wg) * 32 + Wg] = __expf(numer - mx) / se;
            }
        }
    }
}

// ---------------- fused out-GEMM: out[b][n][m] = x + D[b][m]*(V·Wn)[m][n] + bn[n] ----------------
__global__ __launch_bounds__(256) void out_gemm(const short* __restrict__ A,
                                                const short* __restrict__ Wt,
                                                const float* __restrict__ Dm,
                                                const float* __restrict__ bnb,
                                                const float* __restrict__ x,
                                                float* __restrict__ out) {
    const int tid = threadIdx.x;
    const int wv = tid >> 6, ln = tid & 63;
    const int m0 = blockIdx.x * 128, n0 = blockIdx.y * 128, b = blockIdx.z;
    const size_t BS = 1024 * 512;
    const short* Ab = A + (size_t)b * BS;

    __shared__ __attribute__((aligned(16))) short As[3][128 * 32];
    __shared__ __attribute__((aligned(16))) short Bs[3][128 * 32];

    floatx4 acc[4][4] = {};
    const int wm = (wv >> 1) * 64, wn = (wv & 1) * 64;
    const int fr = ln & 15, fq = ln >> 4;

    int sr[2], sq[2];
#pragma unroll
    for (int j = 0; j < 2; ++j) {
        int s = (wv * 2 + j) * 64 + ln;
        sr[j] = s >> 2;
        sq[j] = ((s & 3) ^ ((sr[j] >> 1) & 3)) * 8;
    }

    short* a0 = &As[0][0]; short* a1 = &As[1][0]; short* a2 = &As[2][0];
    short* b0 = &Bs[0][0]; short* b1 = &Bs[1][0]; short* b2 = &Bs[2][0];

#pragma unroll
    for (int j = 0; j < 2; ++j) {
        gl2lds16(Ab + (size_t)(m0 + sr[j]) * 512 + sq[j],      a0 + (wv * 2 + j) * 512);
        gl2lds16(Wt + (size_t)(n0 + sr[j]) * 512 + sq[j],      b0 + (wv * 2 + j) * 512);
        gl2lds16(Ab + (size_t)(m0 + sr[j]) * 512 + 32 + sq[j], a1 + (wv * 2 + j) * 512);
        gl2lds16(Wt + (size_t)(n0 + sr[j]) * 512 + 32 + sq[j], b1 + (wv * 2 + j) * 512);
    }

    auto compute = [&](const short* Ap, const short* Bp) {
        short8 af[4], bfr[4];
#pragma unroll
        for (int t = 0; t < 4; ++t) {
            int ra = wm + t * 16 + fr;
            af[t]  = *(const short8*)(Ap + ra * 32 + ((fq ^ ((ra >> 1) & 3)) * 8));
            int rb = wn + t * 16 + fr;
            bfr[t] = *(const short8*)(Bp + rb * 32 + ((fq ^ ((rb >> 1) & 3)) * 8));
        }
#pragma unroll
        for (int mt = 0; mt < 4; ++mt)
#pragma unroll
            for (int nt = 0; nt < 4; ++nt)
                acc[mt][nt] = MFMA16(af[mt], bfr[nt], acc[mt][nt]);
    };

    for (int t = 0; t < 14; ++t) {
        int kp = t * 32 + 64;
#pragma unroll
        for (int j = 0; j < 2; ++j) {
            gl2lds16(Ab + (size_t)(m0 + sr[j]) * 512 + kp + sq[j], a2 + (wv * 2 + j) * 512);
            gl2lds16(Wt + (size_t)(n0 + sr[j]) * 512 + kp + sq[j], b2 + (wv * 2 + j) * 512);
        }
        WAIT_VM(8);
        BAR();
        compute(a0, b0);
        BAR();
        short* ta = a0; a0 = a1; a1 = a2; a2 = ta;
        short* tb = b0; b0 = b1; b1 = b2; b2 = tb;
    }
    WAIT_VM(4); BAR();
    compute(a0, b0);
    WAIT_VM(0); BAR();
    compute(a1, b1);

#pragma unroll
    for (int mt = 0; mt < 4; ++mt) {
        int mbase = m0 + wm + mt * 16 + fq * 4;
        float4 d4 = *(const float4*)(Dm + (size_t)b * 1024 + mbase);
#pragma unroll
        for (int nt = 0; nt < 4; ++nt) {
            int n = n0 + wn + nt * 16 + fr;
            float bvv = bnb[n];
            size_t base = ((size_t)b * 512 + n) * 1024 + mbase;
            float4 x4 = *(const float4*)(x + base);
            float4 o;
            o.x = x4.x + d4.x * acc[mt][nt][0] + bvv;
            o.y = x4.y + d4.y * acc[mt][nt][1] + bvv;
            o.z = x4.z + d4.z * acc[mt][nt][2] + bvv;
            o.w = x4.w + d4.w * acc[mt][nt][3] + bvv;
            *(float4*)(out + base) = o;
        }
    }
}

extern "C" void kernel_launch(void* const* d_in, const int* in_sizes, int n_in,
                              void* d_out, int out_size, void* d_ws, size_t ws_size,
                              hipStream_t stream) {
    const float* x  = (const float*)d_in[0];
    const float* Wq = (const float*)d_in[1];
    const float* bq = (const float*)d_in[2];
    const float* Wk = (const float*)d_in[3];
    const float* bk = (const float*)d_in[4];
    const float* Wv = (const float*)d_in[5];
    const float* bv = (const float*)d_in[6];
    const float* Wn = (const float*)d_in[7];
    const float* bn = (const float*)d_in[8];
    float* out = (float*)d_out;
    char* ws = (char*)d_ws;

    const size_t WQKV = (size_t)1536 * 512 * 2;       // 1.57 MB
    const size_t WSZ  = (size_t)512 * 512 * 2;        // 0.52 MB
    const size_t BIAS = 1536 * sizeof(float);
    const size_t TSZ  = (size_t)16 * 1024 * 512 * 2;  // 16.78 MB
    short* Wqkv_t   = (short*)(ws);
    short* Wn_t     = (short*)(ws + WQKV);
    float* bias_cat = (float*)(ws + WQKV + WSZ);
    char*  base     = ws + WQKV + WSZ + BIAS;
    short* hnt = (short*)(base);
    short* Qp  = (short*)(base + TSZ);
    short* Kp  = (short*)(base + 2 * TSZ);
    short* Vb  = (short*)(base + 3 * TSZ);
    float* Dm  = (float*)(base + 4 * TSZ);            // 16*1024 fp32

    transpose_w4<<<dim3(16, 16, 4), dim3(32, 8), 0, stream>>>(
        Wq, Wk, Wv, Wn, bq, bk, bv, Wqkv_t, Wn_t, bias_cat);
    groupnorm_k<<<512, 256, 0, stream>>>(x, hnt);
    qkv_gemm<<<dim3(8, 12, 16), 256, 0, stream>>>(hnt, Wqkv_t, bias_cat, Qp, Kp, Vb);
    attn_sm<<<dim3(8, 4, 16), 256, 0, stream>>>(Qp, Kp, Dm);
    out_gemm<<<dim3(8, 4, 16), 256, 0, stream>>>(Vb, Wn_t, Dm, bn, x, out);
}

// Round 3
// 199.351 us; speedup vs baseline: 1.0595x; 1.0595x over previous
//
#include <hip/hip_runtime.h>
#include <hip/hip_bf16.h>

typedef __attribute__((ext_vector_type(8))) short short8;
typedef __attribute__((ext_vector_type(4))) float floatx4;

#define MFMA16(a, b, c) __builtin_amdgcn_mfma_f32_16x16x32_bf16((a), (b), (c), 0, 0, 0)
#define WAIT_VM(N) asm volatile("s_waitcnt vmcnt(" #N ")" ::: "memory")
#define BAR() __builtin_amdgcn_s_barrier()

__device__ __forceinline__ short f2bf(float f) {
    union { float f; unsigned u; } x; x.f = f;
    unsigned r = (x.u + 0x7fffu + ((x.u >> 16) & 1u)) >> 16;
    return (short)r;
}

// async global->LDS, 16B per lane; LDS dest is wave-uniform base + lane*16
__device__ __forceinline__ void gl2lds16(const short* g, short* l) {
    void* gv = const_cast<short*>(g);
    __builtin_amdgcn_global_load_lds((__attribute__((address_space(1))) void*)gv,
                                     (__attribute__((address_space(3))) void*)l,
                                     16, 0, 0);
}

// ------------- weight prep: 4 transposes (fp32->bf16) + bias concat, one launch -------------
__global__ void transpose_w4(const float* __restrict__ Wq, const float* __restrict__ Wk,
                             const float* __restrict__ Wv, const float* __restrict__ Wn,
                             const float* __restrict__ bq, const float* __restrict__ bk,
                             const float* __restrict__ bv,
                             short* __restrict__ Wqkv_t, short* __restrict__ Wn_t,
                             float* __restrict__ bias_cat) {
    __shared__ float t[32][33];
    int z = blockIdx.z;
    const float* Wsrc = (z == 0) ? Wq : (z == 1) ? Wk : (z == 2) ? Wv : Wn;
    int o0 = blockIdx.x * 32, c0 = blockIdx.y * 32;
    int lx = threadIdx.x, ly = threadIdx.y;   // (32,8)
    for (int i = ly; i < 32; i += 8) t[i][lx] = Wsrc[(size_t)(c0 + i) * 512 + o0 + lx];
    __syncthreads();
    for (int i = ly; i < 32; i += 8) {
        short v = f2bf(t[lx][i]);
        if (z < 3) Wqkv_t[(size_t)(z * 512 + o0 + i) * 512 + c0 + lx] = v;
        else       Wn_t[(size_t)(o0 + i) * 512 + c0 + lx] = v;
    }
    if (z < 3 && blockIdx.y == 0 && ly == 0) {
        const float* bsrc = (z == 0) ? bq : (z == 1) ? bk : bv;
        bias_cat[z * 512 + o0 + lx] = bsrc[o0 + lx];
    }
}

// ---------------- groupnorm: x[b][c][p] -> hnt[b][p][c] bf16 ----------------
__global__ __launch_bounds__(256) void groupnorm_k(const float* __restrict__ x,
                                                   short* __restrict__ hnt) {
    int b = blockIdx.x >> 5, g = blockIdx.x & 31;
    const float* xg = x + ((size_t)b * 512 + g * 16) * 1024;   // 16 rows x 1024
    const float4* xg4 = (const float4*)xg;
    float s = 0.f, ss = 0.f;
    for (int i = threadIdx.x; i < 4096; i += 256) {
        float4 v = xg4[i];
        s  += v.x + v.y + v.z + v.w;
        ss += v.x * v.x + v.y * v.y + v.z * v.z + v.w * v.w;
    }
#pragma unroll
    for (int off = 32; off > 0; off >>= 1) {
        s  += __shfl_down(s,  off, 64);
        ss += __shfl_down(ss, off, 64);
    }
    __shared__ float red[8];
    int w = threadIdx.x >> 6;
    if ((threadIdx.x & 63) == 0) { red[w] = s; red[4 + w] = ss; }
    __syncthreads();
    float S  = red[0] + red[1] + red[2] + red[3];
    float SS = red[4] + red[5] + red[6] + red[7];
    float mean = S * (1.f / 16384.f);
    float var  = SS * (1.f / 16384.f) - mean * mean;
    float rstd = rsqrtf(var + 1e-5f);
    __shared__ __attribute__((aligned(16))) short tile[16 * 1026];
    for (int i = threadIdx.x; i < 4096; i += 256) {
        float4 v = xg4[i];
        int c = i >> 8, p = (i & 255) * 4;
        short* tp = tile + c * 1026 + p;
        tp[0] = f2bf((v.x - mean) * rstd);
        tp[1] = f2bf((v.y - mean) * rstd);
        tp[2] = f2bf((v.z - mean) * rstd);
        tp[3] = f2bf((v.w - mean) * rstd);
    }
    __syncthreads();
    for (int i = threadIdx.x; i < 2048; i += 256) {
        int p = i >> 1, half = i & 1;
        short8 v;
#pragma unroll
        for (int j = 0; j < 8; ++j) v[j] = tile[(half * 8 + j) * 1026 + p];
        *(short8*)(hnt + ((size_t)b * 1024 + p) * 512 + g * 16 + half * 8) = v;
    }
}

// ---------------- fused QKV GEMM: N=1536 over concat weights ----------------
// XCD-clustered block remap: each XCD owns 2 complete batches so A-panel re-reads
// (x12) and weight re-reads hit the local 4MB L2 instead of L3.
__global__ __launch_bounds__(256) void qkv_gemm(const short* __restrict__ A,
                                                const short* __restrict__ Wt,
                                                const float* __restrict__ bias_cat,
                                                short* __restrict__ Qp,
                                                short* __restrict__ Kp,
                                                short* __restrict__ Vb) {
    const int tid = threadIdx.x;
    const int wv = tid >> 6, ln = tid & 63;
    // flat id in [0,1536); xcd = fid%8; each xcd gets 192 slots = 2 batches x 96 tiles
    const int fid = blockIdx.x + (blockIdx.y << 3) + blockIdx.z * 96;
    const int xcd = fid & 7, slot = fid >> 3;
    const int bb = (slot >= 96) ? 1 : 0;
    const int w = slot - bb * 96;            // [0,96): m fastest
    const int batch = xcd * 2 + bb;
    const int m0 = (w & 7) * 128, n0 = (w >> 3) * 128;
    const size_t BS = 1024 * 512;
    const short* Ab = A + (size_t)batch * BS;
    const int tsel = n0 >> 9;
    const int permute = (tsel < 2);
    short* Ob = ((tsel == 0) ? Qp : (tsel == 1) ? Kp : Vb) + (size_t)batch * BS;

    __shared__ __attribute__((aligned(16))) short As[3][128 * 32];
    __shared__ __attribute__((aligned(16))) short Bs[3][128 * 32];

    floatx4 acc[4][4] = {};
    const int wm = (wv >> 1) * 64, wn = (wv & 1) * 64;
    const int fr = ln & 15, fq = ln >> 4;

    int sr[2], sq[2];
#pragma unroll
    for (int j = 0; j < 2; ++j) {
        int s = (wv * 2 + j) * 64 + ln;
        sr[j] = s >> 2;
        sq[j] = ((s & 3) ^ ((sr[j] >> 1) & 3)) * 8;
    }
    // loop-invariant LDS fragment read offsets
    int aoff[4], boff[4];
#pragma unroll
    for (int t = 0; t < 4; ++t) {
        int ra = wm + t * 16 + fr;
        aoff[t] = ra * 32 + ((fq ^ ((ra >> 1) & 3)) * 8);
        int rb = wn + t * 16 + fr;
        boff[t] = rb * 32 + ((fq ^ ((rb >> 1) & 3)) * 8);
    }

    short* a0 = &As[0][0]; short* a1 = &As[1][0]; short* a2 = &As[2][0];
    short* b0 = &Bs[0][0]; short* b1 = &Bs[1][0]; short* b2 = &Bs[2][0];

    // stage tiles 0 and 1 (4 loads each per wave)
#pragma unroll
    for (int j = 0; j < 2; ++j) {
        gl2lds16(Ab + (size_t)(m0 + sr[j]) * 512 + sq[j],      a0 + (wv * 2 + j) * 512);
        gl2lds16(Wt + (size_t)(n0 + sr[j]) * 512 + sq[j],      b0 + (wv * 2 + j) * 512);
        gl2lds16(Ab + (size_t)(m0 + sr[j]) * 512 + 32 + sq[j], a1 + (wv * 2 + j) * 512);
        gl2lds16(Wt + (size_t)(n0 + sr[j]) * 512 + 32 + sq[j], b1 + (wv * 2 + j) * 512);
    }

    auto compute = [&](const short* Ap, const short* Bp) {
        short8 af[4], bfr[4];
#pragma unroll
        for (int t = 0; t < 4; ++t) {
            af[t]  = *(const short8*)(Ap + aoff[t]);
            bfr[t] = *(const short8*)(Bp + boff[t]);
        }
#pragma unroll
        for (int mt = 0; mt < 4; ++mt)
#pragma unroll
            for (int nt = 0; nt < 4; ++nt)
                acc[mt][nt] = MFMA16(af[mt], bfr[nt], acc[mt][nt]);
    };

    for (int t = 0; t < 14; ++t) {
        int kp = t * 32 + 64;   // prefetch tile t+2
#pragma unroll
        for (int j = 0; j < 2; ++j) {
            gl2lds16(Ab + (size_t)(m0 + sr[j]) * 512 + kp + sq[j], a2 + (wv * 2 + j) * 512);
            gl2lds16(Wt + (size_t)(n0 + sr[j]) * 512 + kp + sq[j], b2 + (wv * 2 + j) * 512);
        }
        WAIT_VM(8);            // tile t's 4 loads (oldest) done; t+1,t+2 in flight
        BAR();
        compute(a0, b0);
        BAR();                 // all waves done reading tile t's buffer; safe to DMA into it
        short* ta = a0; a0 = a1; a1 = a2; a2 = ta;
        short* tb = b0; b0 = b1; b1 = b2; b2 = tb;
    }
    WAIT_VM(4); BAR();
    compute(a0, b0);           // tile 14
    WAIT_VM(0); BAR();
    compute(a1, b1);           // tile 15

#pragma unroll
    for (int mt = 0; mt < 4; ++mt) {
#pragma unroll
        for (int nt = 0; nt < 4; ++nt) {
            int n = n0 + wn + nt * 16 + fr;
            float bvv = bias_cat[n];
            int nn = n & 511;
#pragma unroll
            for (int r = 0; r < 4; ++r) {
                int m = m0 + wm + mt * 16 + fq * 4 + r;
                int mrow = permute ? ((m & 31) * 32 + (m >> 5)) : m;
                Ob[(size_t)mrow * 512 + nn] = f2bf(acc[mt][nt][r] + bvv);
            }
        }
    }
}

// ---------------- fused S-GEMM + per-32x32-block softmax diagonal, 128x256 tiles ----------------
__global__ __launch_bounds__(256, 2) void attn_sm(const short* __restrict__ Qp,
                                                  const short* __restrict__ Kp,
                                                  float* __restrict__ Dm) {
    const int tid = threadIdx.x;
    const int wv = tid >> 6, ln = tid & 63;
    // flat id in [0,512); each xcd gets 64 slots = 2 batches x 32 tiles
    const int fid = blockIdx.x + (blockIdx.y << 3) + blockIdx.z * 32;
    const int xcd = fid & 7, slot = fid >> 3;
    const int bb = (slot >= 32) ? 1 : 0;
    const int w = slot - bb * 32;            // [0,32)
    const int b = xcd * 2 + bb;
    const int m0 = (w & 7) * 128, n0 = (w >> 3) * 256;
    const short* Qb = Qp + (size_t)b * (1024 * 512);
    const short* Kb = Kp + (size_t)b * (1024 * 512);

    __shared__ __attribute__((aligned(16))) short As[3][128 * 32];
    __shared__ __attribute__((aligned(16))) short Bs[3][256 * 32];

    floatx4 acc[4][8] = {};
    const int wm = (wv >> 1) * 64, wn = (wv & 1) * 128;
    const int fr = ln & 15, fq = ln >> 4;

    int ar[2], aq[2], br[4], bq_[4];
#pragma unroll
    for (int j = 0; j < 2; ++j) {
        int s = (wv * 2 + j) * 64 + ln;
        ar[j] = s >> 2;
        aq[j] = ((s & 3) ^ ((ar[j] >> 1) & 3)) * 8;
    }
#pragma unroll
    for (int j = 0; j < 4; ++j) {
        int s = (wv * 4 + j) * 64 + ln;
        br[j] = s >> 2;
        bq_[j] = ((s & 3) ^ ((br[j] >> 1) & 3)) * 8;
    }
    int aoff[4], boff[8];
#pragma unroll
    for (int t = 0; t < 4; ++t) {
        int ra = wm + t * 16 + fr;
        aoff[t] = ra * 32 + ((fq ^ ((ra >> 1) & 3)) * 8);
    }
#pragma unroll
    for (int u = 0; u < 8; ++u) {
        int rb = wn + u * 16 + fr;
        boff[u] = rb * 32 + ((fq ^ ((rb >> 1) & 3)) * 8);
    }

    short* a0 = &As[0][0]; short* a1 = &As[1][0]; short* a2 = &As[2][0];
    short* b0 = &Bs[0][0]; short* b1 = &Bs[1][0]; short* b2 = &Bs[2][0];

    // stage tiles 0 and 1 (6 loads each per wave)
#pragma unroll
    for (int j = 0; j < 2; ++j) {
        gl2lds16(Qb + (size_t)(m0 + ar[j]) * 512 + aq[j],      a0 + (wv * 2 + j) * 512);
        gl2lds16(Qb + (size_t)(m0 + ar[j]) * 512 + 32 + aq[j], a1 + (wv * 2 + j) * 512);
    }
#pragma unroll
    for (int j = 0; j < 4; ++j) {
        gl2lds16(Kb + (size_t)(n0 + br[j]) * 512 + bq_[j],      b0 + (wv * 4 + j) * 512);
        gl2lds16(Kb + (size_t)(n0 + br[j]) * 512 + 32 + bq_[j], b1 + (wv * 4 + j) * 512);
    }

    auto compute = [&](const short* Ap, const short* Bp) {
        short8 af[4], bfr[8];
#pragma unroll
        for (int t = 0; t < 4; ++t) af[t] = *(const short8*)(Ap + aoff[t]);
#pragma unroll
        for (int u = 0; u < 8; ++u) bfr[u] = *(const short8*)(Bp + boff[u]);
#pragma unroll
        for (int mt = 0; mt < 4; ++mt)
#pragma unroll
            for (int nt = 0; nt < 8; ++nt)
                acc[mt][nt] = MFMA16(af[mt], bfr[nt], acc[mt][nt]);
    };

    for (int t = 0; t < 14; ++t) {
        int kp = t * 32 + 64;   // prefetch tile t+2
#pragma unroll
        for (int j = 0; j < 2; ++j)
            gl2lds16(Qb + (size_t)(m0 + ar[j]) * 512 + kp + aq[j], a2 + (wv * 2 + j) * 512);
#pragma unroll
        for (int j = 0; j < 4; ++j)
            gl2lds16(Kb + (size_t)(n0 + br[j]) * 512 + kp + bq_[j], b2 + (wv * 4 + j) * 512);
        WAIT_VM(12);           // tile t's 6 loads done; 12 newer in flight
        BAR();
        compute(a0, b0);
        BAR();
        short* ta = a0; a0 = a1; a1 = a2; a2 = ta;
        short* tb = b0; b0 = b1; b1 = b2; b2 = tb;
    }
    WAIT_VM(6); BAR();
    compute(a0, b0);           // tile 14
    WAIT_VM(0); BAR();
    compute(a1, b1);           // tile 15

    // ---- per-slice softmax-diagonal (2x4 = 8 slices per wave) ----
    const float scale = 0.04419417382415922f;  // 512^-0.5
    const int wbase = (m0 + wm) >> 5;
    const int Wbase = (n0 + wn) >> 5;
#pragma unroll
    for (int si = 0; si < 2; ++si) {
#pragma unroll
        for (int sj = 0; sj < 4; ++sj) {
            int wg = wbase + si, Wg = Wbase + sj;
            float tv[16];
            float mx = -3.0e38f;
#pragma unroll
            for (int mi = 0; mi < 2; ++mi)
#pragma unroll
                for (int ni = 0; ni < 2; ++ni)
#pragma unroll
                    for (int r = 0; r < 4; ++r) {
                        float u = acc[2 * si + mi][2 * sj + ni][r] * scale;
                        tv[(mi * 2 + ni) * 4 + r] = u;
                        mx = fmaxf(mx, u);
                    }
#pragma unroll
            for (int off = 32; off > 0; off >>= 1) mx = fmaxf(mx, __shfl_xor(mx, off, 64));
            float se = 0.f;
#pragma unroll
            for (int i = 0; i < 16; ++i) se += __expf(tv[i] - mx);
#pragma unroll
            for (int off = 32; off > 0; off >>= 1) se += __shfl_xor(se, off, 64);
            if (fq == ((wg >> 2) & 3) && fr == (Wg & 15)) {
                int mi = wg >> 4, ni = Wg >> 4;
                float numer = tv[(mi * 2 + ni) * 4 + (wg & 3)];
                Dm[((size_t)b * 32 + wg) * 32 + Wg] = __expf(numer - mx) / se;
            }
        }
    }
}

// ---------------- fused out-GEMM: out[b][n][m] = x + D[b][m]*(V·Wn)[m][n] + bn[n] ----------------
__global__ __launch_bounds__(256) void out_gemm(const short* __restrict__ A,
                                                const short* __restrict__ Wt,
                                                const float* __restrict__ Dm,
                                                const float* __restrict__ bnb,
                                                const float* __restrict__ x,
                                                float* __restrict__ out) {
    const int tid = threadIdx.x;
    const int wv = tid >> 6, ln = tid & 63;
    const int fid = blockIdx.x + (blockIdx.y << 3) + blockIdx.z * 32;
    const int xcd = fid & 7, slot = fid >> 3;
    const int bb = (slot >= 32) ? 1 : 0;
    const int w = slot - bb * 32;
    const int b = xcd * 2 + bb;
    const int m0 = (w & 7) * 128, n0 = (w >> 3) * 128;
    const size_t BS = 1024 * 512;
    const short* Ab = A + (size_t)b * BS;

    __shared__ __attribute__((aligned(16))) short As[3][128 * 32];
    __shared__ __attribute__((aligned(16))) short Bs[3][128 * 32];

    floatx4 acc[4][4] = {};
    const int wm = (wv >> 1) * 64, wn = (wv & 1) * 64;
    const int fr = ln & 15, fq = ln >> 4;

    int sr[2], sq[2];
#pragma unroll
    for (int j = 0; j < 2; ++j) {
        int s = (wv * 2 + j) * 64 + ln;
        sr[j] = s >> 2;
        sq[j] = ((s & 3) ^ ((sr[j] >> 1) & 3)) * 8;
    }
    int aoff[4], boff[4];
#pragma unroll
    for (int t = 0; t < 4; ++t) {
        int ra = wm + t * 16 + fr;
        aoff[t] = ra * 32 + ((fq ^ ((ra >> 1) & 3)) * 8);
        int rb = wn + t * 16 + fr;
        boff[t] = rb * 32 + ((fq ^ ((rb >> 1) & 3)) * 8);
    }

    short* a0 = &As[0][0]; short* a1 = &As[1][0]; short* a2 = &As[2][0];
    short* b0 = &Bs[0][0]; short* b1 = &Bs[1][0]; short* b2 = &Bs[2][0];

#pragma unroll
    for (int j = 0; j < 2; ++j) {
        gl2lds16(Ab + (size_t)(m0 + sr[j]) * 512 + sq[j],      a0 + (wv * 2 + j) * 512);
        gl2lds16(Wt + (size_t)(n0 + sr[j]) * 512 + sq[j],      b0 + (wv * 2 + j) * 512);
        gl2lds16(Ab + (size_t)(m0 + sr[j]) * 512 + 32 + sq[j], a1 + (wv * 2 + j) * 512);
        gl2lds16(Wt + (size_t)(n0 + sr[j]) * 512 + 32 + sq[j], b1 + (wv * 2 + j) * 512);
    }

    auto compute = [&](const short* Ap, const short* Bp) {
        short8 af[4], bfr[4];
#pragma unroll
        for (int t = 0; t < 4; ++t) {
            af[t]  = *(const short8*)(Ap + aoff[t]);
            bfr[t] = *(const short8*)(Bp + boff[t]);
        }
#pragma unroll
        for (int mt = 0; mt < 4; ++mt)
#pragma unroll
            for (int nt = 0; nt < 4; ++nt)
                acc[mt][nt] = MFMA16(af[mt], bfr[nt], acc[mt][nt]);
    };

    for (int t = 0; t < 14; ++t) {
        int kp = t * 32 + 64;
#pragma unroll
        for (int j = 0; j < 2; ++j) {
            gl2lds16(Ab + (size_t)(m0 + sr[j]) * 512 + kp + sq[j], a2 + (wv * 2 + j) * 512);
            gl2lds16(Wt + (size_t)(n0 + sr[j]) * 512 + kp + sq[j], b2 + (wv * 2 + j) * 512);
        }
        WAIT_VM(8);
        BAR();
        compute(a0, b0);
        BAR();
        short* ta = a0; a0 = a1; a1 = a2; a2 = ta;
        short* tb = b0; b0 = b1; b1 = b2; b2 = tb;
    }
    WAIT_VM(4); BAR();
    compute(a0, b0);
    WAIT_VM(0); BAR();
    compute(a1, b1);

#pragma unroll
    for (int mt = 0; mt < 4; ++mt) {
        int mbase = m0 + wm + mt * 16 + fq * 4;
        float4 d4 = *(const float4*)(Dm + (size_t)b * 1024 + mbase);
#pragma unroll
        for (int nt = 0; nt < 4; ++nt) {
            int n = n0 + wn + nt * 16 + fr;
            float bvv = bnb[n];
            size_t base = ((size_t)b * 512 + n) * 1024 + mbase;
            float4 x4 = *(const float4*)(x + base);
            float4 o;
            o.x = x4.x + d4.x * acc[mt][nt][0] + bvv;
            o.y = x4.y + d4.y * acc[mt][nt][1] + bvv;
            o.z = x4.z + d4.z * acc[mt][nt][2] + bvv;
            o.w = x4.w + d4.w * acc[mt][nt][3] + bvv;
            *(float4*)(out + base) = o;
        }
    }
}

extern "C" void kernel_launch(void* const* d_in, const int* in_sizes, int n_in,
                              void* d_out, int out_size, void* d_ws, size_t ws_size,
                              hipStream_t stream) {
    const float* x  = (const float*)d_in[0];
    const float* Wq = (const float*)d_in[1];
    const float* bq = (const float*)d_in[2];
    const float* Wk = (const float*)d_in[3];
    const float* bk = (const float*)d_in[4];
    const float* Wv = (const float*)d_in[5];
    const float* bv = (const float*)d_in[6];
    const float* Wn = (const float*)d_in[7];
    const float* bn = (const float*)d_in[8];
    float* out = (float*)d_out;
    char* ws = (char*)d_ws;

    const size_t WQKV = (size_t)1536 * 512 * 2;       // 1.57 MB
    const size_t WSZ  = (size_t)512 * 512 * 2;        // 0.52 MB
    const size_t BIAS = 1536 * sizeof(float);
    const size_t TSZ  = (size_t)16 * 1024 * 512 * 2;  // 16.78 MB
    short* Wqkv_t   = (short*)(ws);
    short* Wn_t     = (short*)(ws + WQKV);
    float* bias_cat = (float*)(ws + WQKV + WSZ);
    char*  base     = ws + WQKV + WSZ + BIAS;
    short* hnt = (short*)(base);
    short* Qp  = (short*)(base + TSZ);
    short* Kp  = (short*)(base + 2 * TSZ);
    short* Vb  = (short*)(base + 3 * TSZ);
    float* Dm  = (float*)(base + 4 * TSZ);            // 16*1024 fp32

    transpose_w4<<<dim3(16, 16, 4), dim3(32, 8), 0, stream>>>(
        Wq, Wk, Wv, Wn, bq, bk, bv, Wqkv_t, Wn_t, bias_cat);
    groupnorm_k<<<512, 256, 0, stream>>>(x, hnt);
    qkv_gemm<<<dim3(8, 12, 16), 256, 0, stream>>>(hnt, Wqkv_t, bias_cat, Qp, Kp, Vb);
    attn_sm<<<dim3(8, 4, 16), 256, 0, stream>>>(Qp, Kp, Dm);
    out_gemm<<<dim3(8, 4, 16), 256, 0, stream>>>(Vb, Wn_t, Dm, bn, x, out);
}

// Round 4
// 199.289 us; speedup vs baseline: 1.0598x; 1.0003x over previous
//
#include <hip/hip_runtime.h>
#include <hip/hip_bf16.h>

typedef __attribute__((ext_vector_type(8))) short short8;
typedef __attribute__((ext_vector_type(4))) float floatx4;

#define MFMA16(a, b, c) __builtin_amdgcn_mfma_f32_16x16x32_bf16((a), (b), (c), 0, 0, 0)
#define WAIT_VM(N) asm volatile("s_waitcnt vmcnt(" #N ")" ::: "memory")
#define BARM() do { asm volatile("" ::: "memory"); __builtin_amdgcn_s_barrier(); asm volatile("" ::: "memory"); } while (0)

__device__ __forceinline__ short f2bf(float f) {
    union { float f; unsigned u; } x; x.f = f;
    unsigned r = (x.u + 0x7fffu + ((x.u >> 16) & 1u)) >> 16;
    return (short)r;
}

// async global->LDS, 16B per lane; LDS dest is wave-uniform base + lane*16
__device__ __forceinline__ void gl2lds16(const short* g, short* l) {
    void* gv = const_cast<short*>(g);
    __builtin_amdgcn_global_load_lds((__attribute__((address_space(1))) void*)gv,
                                     (__attribute__((address_space(3))) void*)l,
                                     16, 0, 0);
}

// ------------- weight prep: 4 transposes (fp32->bf16) + bias concat, one launch -------------
__global__ void transpose_w4(const float* __restrict__ Wq, const float* __restrict__ Wk,
                             const float* __restrict__ Wv, const float* __restrict__ Wn,
                             const float* __restrict__ bq, const float* __restrict__ bk,
                             const float* __restrict__ bv,
                             short* __restrict__ Wqkv_t, short* __restrict__ Wn_t,
                             float* __restrict__ bias_cat) {
    __shared__ float t[32][33];
    int z = blockIdx.z;
    const float* Wsrc = (z == 0) ? Wq : (z == 1) ? Wk : (z == 2) ? Wv : Wn;
    int o0 = blockIdx.x * 32, c0 = blockIdx.y * 32;
    int lx = threadIdx.x, ly = threadIdx.y;   // (32,8)
    for (int i = ly; i < 32; i += 8) t[i][lx] = Wsrc[(size_t)(c0 + i) * 512 + o0 + lx];
    __syncthreads();
    for (int i = ly; i < 32; i += 8) {
        short v = f2bf(t[lx][i]);
        if (z < 3) Wqkv_t[(size_t)(z * 512 + o0 + i) * 512 + c0 + lx] = v;
        else       Wn_t[(size_t)(o0 + i) * 512 + c0 + lx] = v;
    }
    if (z < 3 && blockIdx.y == 0 && ly == 0) {
        const float* bsrc = (z == 0) ? bq : (z == 1) ? bk : bv;
        bias_cat[z * 512 + o0 + lx] = bsrc[o0 + lx];
    }
}

// ---------------- groupnorm: x[b][c][p] -> hnt[b][p][c] bf16 ----------------
__global__ __launch_bounds__(256) void groupnorm_k(const float* __restrict__ x,
                                                   short* __restrict__ hnt) {
    int b = blockIdx.x >> 5, g = blockIdx.x & 31;
    const float* xg = x + ((size_t)b * 512 + g * 16) * 1024;   // 16 rows x 1024
    const float4* xg4 = (const float4*)xg;
    float s = 0.f, ss = 0.f;
    for (int i = threadIdx.x; i < 4096; i += 256) {
        float4 v = xg4[i];
        s  += v.x + v.y + v.z + v.w;
        ss += v.x * v.x + v.y * v.y + v.z * v.z + v.w * v.w;
    }
#pragma unroll
    for (int off = 32; off > 0; off >>= 1) {
        s  += __shfl_down(s,  off, 64);
        ss += __shfl_down(ss, off, 64);
    }
    __shared__ float red[8];
    int w = threadIdx.x >> 6;
    if ((threadIdx.x & 63) == 0) { red[w] = s; red[4 + w] = ss; }
    __syncthreads();
    float S  = red[0] + red[1] + red[2] + red[3];
    float SS = red[4] + red[5] + red[6] + red[7];
    float mean = S * (1.f / 16384.f);
    float var  = SS * (1.f / 16384.f) - mean * mean;
    float rstd = rsqrtf(var + 1e-5f);
    __shared__ __attribute__((aligned(16))) short tile[16 * 1026];
    for (int i = threadIdx.x; i < 4096; i += 256) {
        float4 v = xg4[i];
        int c = i >> 8, p = (i & 255) * 4;
        short* tp = tile + c * 1026 + p;
        tp[0] = f2bf((v.x - mean) * rstd);
        tp[1] = f2bf((v.y - mean) * rstd);
        tp[2] = f2bf((v.z - mean) * rstd);
        tp[3] = f2bf((v.w - mean) * rstd);
    }
    __syncthreads();
    for (int i = threadIdx.x; i < 2048; i += 256) {
        int p = i >> 1, half = i & 1;
        short8 v;
#pragma unroll
        for (int j = 0; j < 8; ++j) v[j] = tile[(half * 8 + j) * 1026 + p];
        *(short8*)(hnt + ((size_t)b * 1024 + p) * 512 + g * 16 + half * 8) = v;
    }
}

// ================= 256x256 / BK=64 8-phase GEMM (T3+T4+T2+T5) =================
// 512 thr = 8 waves (2M x 4N). LDS: A[2][256x64] + B[2][256x64] bf16 = 128 KB.
// Per K-tile: 4 phases {ds_read subtile | 2x global_load_lds prefetch | bar |
// MFMA x16 (setprio) | bar}, counted vmcnt(4)/vmcnt(2) only - never drained.
// LDS rows are 128B; chunk c of row r holds global chunk c^(r&7) (pre-swizzled
// global source, linear LDS dest) -> ds_read_b128 is 2-way (free).

// ---------------- fused QKV GEMM: M=16384 (batch-stacked), N=1536, K=512 ----------------
__global__ __launch_bounds__(512, 2) void qkv_gemm256(const short* __restrict__ A,
                                                      const short* __restrict__ Wt,
                                                      const float* __restrict__ bias_cat,
                                                      short* __restrict__ Qp,
                                                      short* __restrict__ Kp,
                                                      short* __restrict__ Vb) {
    const int tid = threadIdx.x;
    const int wid = tid >> 6, ln = tid & 63;
    const int wrow = wid >> 2, wcol = wid & 3;
    // 384 blocks = 8 XCD x 48; each XCD gets 8 contiguous m-tiles x all 6 n-tiles
    const int fid = blockIdx.x;
    const int xcd = fid & 7, s = fid >> 3;          // s in [0,48)
    const int mt = xcd * 8 + s / 6, nt = s % 6;
    const int m0 = mt * 256, n0 = nt * 256;
    const int tsel = n0 >> 9;
    const int permute = (tsel < 2);
    short* Ob = (tsel == 0) ? Qp : (tsel == 1) ? Kp : Vb;

    __shared__ __attribute__((aligned(16))) short Asb[2][256 * 64];
    __shared__ __attribute__((aligned(16))) short Bsb[2][256 * 64];

    floatx4 acc[8][4] = {};
    const int fr = ln & 15, fq = ln >> 4;

    // staging: load j covers rows j*64 + wid*8 + (ln>>3); phys chunk ln&7 holds
    // global chunk (ln&7)^((ln>>3)&7)   [row&7 == (ln>>3)&7]
    const int srow = wid * 8 + (ln >> 3);
    const int schk = (ln & 7) ^ ((ln >> 3) & 7);
    const short* gA = A + (size_t)(m0 + srow) * 512 + schk * 8;
    const short* gB = Wt + (size_t)(n0 + srow) * 512 + schk * 8;

    short* Ac = &Asb[0][0]; short* Bc = &Bsb[0][0];
    short* An = &Asb[1][0]; short* Bn = &Bsb[1][0];

    auto SA = [&](int j, short* db) { gl2lds16(gA + (size_t)j * 32768, db + j * 4096 + wid * 512); };
    auto SB = [&](int j, short* db) { gl2lds16(gB + (size_t)j * 32768, db + j * 4096 + wid * 512); };
    auto LDA = [&](const short* Ap, int mh, int ks, short8* dst) {
#pragma unroll
        for (int t = 0; t < 4; ++t) {
            int ra = wrow * 128 + (mh * 4 + t) * 16 + fr;
            dst[t] = *(const short8*)(Ap + ra * 64 + (((ks << 2) | fq) ^ (fr & 7)) * 8);
        }
    };
    auto LDB = [&](const short* Bp, int ks, short8* dst) {
#pragma unroll
        for (int nf = 0; nf < 4; ++nf) {
            int rb = wcol * 64 + nf * 16 + fr;
            dst[nf] = *(const short8*)(Bp + rb * 64 + (((ks << 2) | fq) ^ (fr & 7)) * 8);
        }
    };
    auto MM = [&](int mh, const short8* a_, const short8* b_) {
        __builtin_amdgcn_s_setprio(1);
#pragma unroll
        for (int t = 0; t < 4; ++t)
#pragma unroll
            for (int nf = 0; nf < 4; ++nf)
                acc[mh * 4 + t][nf] = MFMA16(a_[t], b_[nf], acc[mh * 4 + t][nf]);
        __builtin_amdgcn_s_setprio(0);
    };

    // prologue: stage K-tile 0 in consumption order; keep newest 2 (A1,A3) in flight
    SA(0, Ac); SA(2, Ac); SB(0, Bc); SB(1, Bc); SB(2, Bc); SB(3, Bc); SA(1, Ac); SA(3, Ac);
    gA += 64; gB += 64;
    WAIT_VM(2);
    BARM();

    short8 a_[4], p0[4], p1[4];
    for (int kt = 0; kt < 8; ++kt) {
        const bool st = (kt < 7);
        // ---- ph0: quadrant (mh0, ks0); prefetch A0,A2 of next K-tile
        LDA(Ac, 0, 0, a_); LDB(Bc, 0, p0);
        if (st) { SA(0, An); SA(2, An); }
        BARM();
        MM(0, a_, p0);
        BARM();
        // ---- ph1: (mh0, ks1); prefetch B0,B1
        LDA(Ac, 0, 1, a_); LDB(Bc, 1, p1);
        if (st) { SB(0, Bn); SB(1, Bn); }
        BARM();
        MM(0, a_, p1);
        if (st) { WAIT_VM(4); } else { WAIT_VM(0); }   // this K-tile's A1,A3 landed
        BARM();
        // ---- ph2: (mh1, ks0); prefetch B2,B3  (B ks0 frags reused from regs)
        LDA(Ac, 1, 0, a_);
        if (st) { SB(2, Bn); SB(3, Bn); }
        BARM();
        MM(1, a_, p0);
        BARM();
        // ---- ph3: (mh1, ks1); prefetch A1,A3
        LDA(Ac, 1, 1, a_);
        if (st) { SA(1, An); SA(3, An); }
        BARM();
        MM(1, a_, p1);
        if (st) { WAIT_VM(2); }                        // next K-tile's A0,A2,B* landed
        BARM();
        short* t0 = Ac; Ac = An; An = t0;
        short* t1 = Bc; Bc = Bn; Bn = t1;
        if (st) { gA += 64; gB += 64; }
    }

    // epilogue
    const size_t BS = 1024 * 512;
#pragma unroll
    for (int mf = 0; mf < 8; ++mf) {
        int m = m0 + wrow * 128 + mf * 16 + fq * 4;
        int batch = m >> 10;
        short* Obb = Ob + (size_t)batch * BS;
#pragma unroll
        for (int nf = 0; nf < 4; ++nf) {
            int n = n0 + wcol * 64 + nf * 16 + fr;
            float bvv = bias_cat[n];
            int nn = n & 511;
#pragma unroll
            for (int r = 0; r < 4; ++r) {
                int p = (m + r) & 1023;
                int mrow = permute ? ((p & 31) * 32 + (p >> 5)) : p;
                Obb[(size_t)mrow * 512 + nn] = f2bf(acc[mf][nf][r] + bvv);
            }
        }
    }
}

// ---------------- fused S-GEMM + per-32x32-block softmax diagonal, 256x256 tiles ----------------
__global__ __launch_bounds__(512, 2) void attn_sm256(const short* __restrict__ Qp,
                                                     const short* __restrict__ Kp,
                                                     float* __restrict__ Dm) {
    const int tid = threadIdx.x;
    const int wid = tid >> 6, ln = tid & 63;
    const int wrow = wid >> 2, wcol = wid & 3;
    // 256 blocks = 8 XCD x 32; each XCD owns 2 batches x 16 tiles
    const int fid = blockIdx.x;
    const int xcd = fid & 7, slot = fid >> 3;       // slot in [0,32)
    const int b = xcd * 2 + (slot >> 4);
    const int t4 = slot & 15;
    const int m0 = (t4 & 3) * 256, n0 = (t4 >> 2) * 256;
    const size_t BS = 1024 * 512;
    const short* Qb = Qp + (size_t)b * BS;
    const short* Kb = Kp + (size_t)b * BS;

    __shared__ __attribute__((aligned(16))) short Asb[2][256 * 64];
    __shared__ __attribute__((aligned(16))) short Bsb[2][256 * 64];

    floatx4 acc[8][4] = {};
    const int fr = ln & 15, fq = ln >> 4;

    const int srow = wid * 8 + (ln >> 3);
    const int schk = (ln & 7) ^ ((ln >> 3) & 7);
    const short* gA = Qb + (size_t)(m0 + srow) * 512 + schk * 8;
    const short* gB = Kb + (size_t)(n0 + srow) * 512 + schk * 8;

    short* Ac = &Asb[0][0]; short* Bc = &Bsb[0][0];
    short* An = &Asb[1][0]; short* Bn = &Bsb[1][0];

    auto SA = [&](int j, short* db) { gl2lds16(gA + (size_t)j * 32768, db + j * 4096 + wid * 512); };
    auto SB = [&](int j, short* db) { gl2lds16(gB + (size_t)j * 32768, db + j * 4096 + wid * 512); };
    auto LDA = [&](const short* Ap, int mh, int ks, short8* dst) {
#pragma unroll
        for (int t = 0; t < 4; ++t) {
            int ra = wrow * 128 + (mh * 4 + t) * 16 + fr;
            dst[t] = *(const short8*)(Ap + ra * 64 + (((ks << 2) | fq) ^ (fr & 7)) * 8);
        }
    };
    auto LDB = [&](const short* Bp, int ks, short8* dst) {
#pragma unroll
        for (int nf = 0; nf < 4; ++nf) {
            int rb = wcol * 64 + nf * 16 + fr;
            dst[nf] = *(const short8*)(Bp + rb * 64 + (((ks << 2) | fq) ^ (fr & 7)) * 8);
        }
    };
    auto MM = [&](int mh, const short8* a_, const short8* b_) {
        __builtin_amdgcn_s_setprio(1);
#pragma unroll
        for (int t = 0; t < 4; ++t)
#pragma unroll
            for (int nf = 0; nf < 4; ++nf)
                acc[mh * 4 + t][nf] = MFMA16(a_[t], b_[nf], acc[mh * 4 + t][nf]);
        __builtin_amdgcn_s_setprio(0);
    };

    SA(0, Ac); SA(2, Ac); SB(0, Bc); SB(1, Bc); SB(2, Bc); SB(3, Bc); SA(1, Ac); SA(3, Ac);
    gA += 64; gB += 64;
    WAIT_VM(2);
    BARM();

    short8 a_[4], p0[4], p1[4];
    for (int kt = 0; kt < 8; ++kt) {
        const bool st = (kt < 7);
        LDA(Ac, 0, 0, a_); LDB(Bc, 0, p0);
        if (st) { SA(0, An); SA(2, An); }
        BARM();
        MM(0, a_, p0);
        BARM();
        LDA(Ac, 0, 1, a_); LDB(Bc, 1, p1);
        if (st) { SB(0, Bn); SB(1, Bn); }
        BARM();
        MM(0, a_, p1);
        if (st) { WAIT_VM(4); } else { WAIT_VM(0); }
        BARM();
        LDA(Ac, 1, 0, a_);
        if (st) { SB(2, Bn); SB(3, Bn); }
        BARM();
        MM(1, a_, p0);
        BARM();
        LDA(Ac, 1, 1, a_);
        if (st) { SA(1, An); SA(3, An); }
        BARM();
        MM(1, a_, p1);
        if (st) { WAIT_VM(2); }
        BARM();
        short* t0 = Ac; Ac = An; An = t0;
        short* t1 = Bc; Bc = Bn; Bn = t1;
        if (st) { gA += 64; gB += 64; }
    }

    // ---- per-slice softmax-diagonal (4x2 = 8 slices per wave) ----
    const float scale = 0.04419417382415922f;  // 512^-0.5
    const int wbase = (m0 + wrow * 128) >> 5;
    const int Wbase = (n0 + wcol * 64) >> 5;
#pragma unroll
    for (int si = 0; si < 4; ++si) {
#pragma unroll
        for (int sj = 0; sj < 2; ++sj) {
            int wg = wbase + si, Wg = Wbase + sj;
            float tv[16];
            float mx = -3.0e38f;
#pragma unroll
            for (int mi = 0; mi < 2; ++mi)
#pragma unroll
                for (int ni = 0; ni < 2; ++ni)
#pragma unroll
                    for (int r = 0; r < 4; ++r) {
                        float u = acc[2 * si + mi][2 * sj + ni][r] * scale;
                        tv[(mi * 2 + ni) * 4 + r] = u;
                        mx = fmaxf(mx, u);
                    }
#pragma unroll
            for (int off = 32; off > 0; off >>= 1) mx = fmaxf(mx, __shfl_xor(mx, off, 64));
            float se = 0.f;
#pragma unroll
            for (int i = 0; i < 16; ++i) se += __expf(tv[i] - mx);
#pragma unroll
            for (int off = 32; off > 0; off >>= 1) se += __shfl_xor(se, off, 64);
            if (fq == ((wg >> 2) & 3) && fr == (Wg & 15)) {
                int mi = wg >> 4, ni = Wg >> 4;
                float numer = tv[(mi * 2 + ni) * 4 + (wg & 3)];
                Dm[((size_t)b * 32 + wg) * 32 + Wg] = __expf(numer - mx) / se;
            }
        }
    }
}

// ---------------- fused out-GEMM: out[b][n][m] = x + D[b][m]*(V.Wn)[m][n] + bn[n] ----------------
__global__ __launch_bounds__(256) void out_gemm(const short* __restrict__ A,
                                                const short* __restrict__ Wt,
                                                const float* __restrict__ Dm,
                                                const float* __restrict__ bnb,
                                                const float* __restrict__ x,
                                                float* __restrict__ out) {
    const int tid = threadIdx.x;
    const int wv = tid >> 6, ln = tid & 63;
    const int fid = blockIdx.x + (blockIdx.y << 3) + blockIdx.z * 32;
    const int xcd = fid & 7, slot = fid >> 3;
    const int bb = (slot >= 32) ? 1 : 0;
    const int w = slot - bb * 32;
    const int b = xcd * 2 + bb;
    const int m0 = (w & 7) * 128, n0 = (w >> 3) * 128;
    const size_t BS = 1024 * 512;
    const short* Ab = A + (size_t)b * BS;

    __shared__ __attribute__((aligned(16))) short As[3][128 * 32];
    __shared__ __attribute__((aligned(16))) short Bs[3][128 * 32];

    floatx4 acc[4][4] = {};
    const int wm = (wv >> 1) * 64, wn = (wv & 1) * 64;
    const int fr = ln & 15, fq = ln >> 4;

    int sr[2], sq[2];
#pragma unroll
    for (int j = 0; j < 2; ++j) {
        int s = (wv * 2 + j) * 64 + ln;
        sr[j] = s >> 2;
        sq[j] = ((s & 3) ^ ((sr[j] >> 1) & 3)) * 8;
    }
    int aoff[4], boff[4];
#pragma unroll
    for (int t = 0; t < 4; ++t) {
        int ra = wm + t * 16 + fr;
        aoff[t] = ra * 32 + ((fq ^ ((ra >> 1) & 3)) * 8);
        int rb = wn + t * 16 + fr;
        boff[t] = rb * 32 + ((fq ^ ((rb >> 1) & 3)) * 8);
    }

    short* a0 = &As[0][0]; short* a1 = &As[1][0]; short* a2 = &As[2][0];
    short* b0 = &Bs[0][0]; short* b1 = &Bs[1][0]; short* b2 = &Bs[2][0];

#pragma unroll
    for (int j = 0; j < 2; ++j) {
        gl2lds16(Ab + (size_t)(m0 + sr[j]) * 512 + sq[j],      a0 + (wv * 2 + j) * 512);
        gl2lds16(Wt + (size_t)(n0 + sr[j]) * 512 + sq[j],      b0 + (wv * 2 + j) * 512);
        gl2lds16(Ab + (size_t)(m0 + sr[j]) * 512 + 32 + sq[j], a1 + (wv * 2 + j) * 512);
        gl2lds16(Wt + (size_t)(n0 + sr[j]) * 512 + 32 + sq[j], b1 + (wv * 2 + j) * 512);
    }

    auto compute = [&](const short* Ap, const short* Bp) {
        short8 af[4], bfr[4];
#pragma unroll
        for (int t = 0; t < 4; ++t) {
            af[t]  = *(const short8*)(Ap + aoff[t]);
            bfr[t] = *(const short8*)(Bp + boff[t]);
        }
#pragma unroll
        for (int mt = 0; mt < 4; ++mt)
#pragma unroll
            for (int nt = 0; nt < 4; ++nt)
                acc[mt][nt] = MFMA16(af[mt], bfr[nt], acc[mt][nt]);
    };

    for (int t = 0; t < 14; ++t) {
        int kp = t * 32 + 64;
#pragma unroll
        for (int j = 0; j < 2; ++j) {
            gl2lds16(Ab + (size_t)(m0 + sr[j]) * 512 + kp + sq[j], a2 + (wv * 2 + j) * 512);
            gl2lds16(Wt + (size_t)(n0 + sr[j]) * 512 + kp + sq[j], b2 + (wv * 2 + j) * 512);
        }
        WAIT_VM(8);
        BARM();
        compute(a0, b0);
        BARM();
        short* ta = a0; a0 = a1; a1 = a2; a2 = ta;
        short* tb = b0; b0 = b1; b1 = b2; b2 = tb;
    }
    WAIT_VM(4); BARM();
    compute(a0, b0);
    WAIT_VM(0); BARM();
    compute(a1, b1);

#pragma unroll
    for (int mt = 0; mt < 4; ++mt) {
        int mbase = m0 + wm + mt * 16 + fq * 4;
        float4 d4 = *(const float4*)(Dm + (size_t)b * 1024 + mbase);
#pragma unroll
        for (int nt = 0; nt < 4; ++nt) {
            int n = n0 + wn + nt * 16 + fr;
            float bvv = bnb[n];
            size_t base = ((size_t)b * 512 + n) * 1024 + mbase;
            float4 x4 = *(const float4*)(x + base);
            float4 o;
            o.x = x4.x + d4.x * acc[mt][nt][0] + bvv;
            o.y = x4.y + d4.y * acc[mt][nt][1] + bvv;
            o.z = x4.z + d4.z * acc[mt][nt][2] + bvv;
            o.w = x4.w + d4.w * acc[mt][nt][3] + bvv;
            *(float4*)(out + base) = o;
        }
    }
}

extern "C" void kernel_launch(void* const* d_in, const int* in_sizes, int n_in,
                              void* d_out, int out_size, void* d_ws, size_t ws_size,
                              hipStream_t stream) {
    const float* x  = (const float*)d_in[0];
    const float* Wq = (const float*)d_in[1];
    const float* bq = (const float*)d_in[2];
    const float* Wk = (const float*)d_in[3];
    const float* bk = (const float*)d_in[4];
    const float* Wv = (const float*)d_in[5];
    const float* bv = (const float*)d_in[6];
    const float* Wn = (const float*)d_in[7];
    const float* bn = (const float*)d_in[8];
    float* out = (float*)d_out;
    char* ws = (char*)d_ws;

    const size_t WQKV = (size_t)1536 * 512 * 2;       // 1.57 MB
    const size_t WSZ  = (size_t)512 * 512 * 2;        // 0.52 MB
    const size_t BIAS = 1536 * sizeof(float);
    const size_t TSZ  = (size_t)16 * 1024 * 512 * 2;  // 16.78 MB
    short* Wqkv_t   = (short*)(ws);
    short* Wn_t     = (short*)(ws + WQKV);
    float* bias_cat = (float*)(ws + WQKV + WSZ);
    char*  base     = ws + WQKV + WSZ + BIAS;
    short* hnt = (short*)(base);
    short* Qp  = (short*)(base + TSZ);
    short* Kp  = (short*)(base + 2 * TSZ);
    short* Vb  = (short*)(base + 3 * TSZ);
    float* Dm  = (float*)(base + 4 * TSZ);            // 16*1024 fp32

    transpose_w4<<<dim3(16, 16, 4), dim3(32, 8), 0, stream>>>(
        Wq, Wk, Wv, Wn, bq, bk, bv, Wqkv_t, Wn_t, bias_cat);
    groupnorm_k<<<512, 256, 0, stream>>>(x, hnt);
    qkv_gemm256<<<384, 512, 0, stream>>>(hnt, Wqkv_t, bias_cat, Qp, Kp, Vb);
    attn_sm256<<<256, 512, 0, stream>>>(Qp, Kp, Dm);
    out_gemm<<<dim3(8, 4, 16), 256, 0, stream>>>(Vb, Wn_t, Dm, bn, x, out);
}